// Round 2
// 765.946 us; speedup vs baseline: 1.1595x; 1.1595x over previous
//
#include <hip/hip_runtime.h>
#include <hip/hip_bf16.h>

typedef __bf16 bf16x8 __attribute__((ext_vector_type(8)));
typedef float f32x4 __attribute__((ext_vector_type(4)));

#define MFMA16(a, b, c) __builtin_amdgcn_mfma_f32_16x16x32_bf16(a, b, c, 0, 0, 0)

#define EMBED 1024
#define NH 16
#define HD 64
#define SEQ 2048
#define BATCH 2
#define MROWS 4096  // BATCH*SEQ
#define SCALING 0.125f
#define MAXC 8.0f   // fixed softmax offset: scores |s*0.125| <= ~3 here, so
                    // exp(s*0.125-8) in [e-11, e-5] -- no overflow/underflow,
                    // algebraically identical to max-subtracted softmax.

// ---------------------------------------------------------------------------
// GEMM: C[M,N] = A[M,K] @ B[N,K]^T + bias[N]
// A: fp32 or bf16 (converted to bf16 at staging), B/bias: fp32 in, bf16 MFMA.
// 128x128 tile, BK=64, 256 thr, 16x16x32 bf16 MFMA. LDS rows padded to 72.
// vmode=1 (bf16 C only): store transposed as (N,H,D,S) for the V projection.
// ---------------------------------------------------------------------------
template <typename T>
__device__ inline void stage_tile(const T* __restrict__ src, int ld,
                                  __hip_bfloat16* __restrict__ dst, int tid) {
    if constexpr (sizeof(T) == 2) {  // bf16: 16B = 8 elems per chunk
#pragma unroll
        for (int i = 0; i < 4; ++i) {
            int idx = tid + i * 256;
            int row = idx >> 3;
            int c   = (idx & 7) * 8;
            *(uint4*)&dst[row * 72 + c] = *(const uint4*)&src[(size_t)row * ld + c];
        }
    } else {  // fp32: 16B = 4 elems per chunk, convert to bf16
#pragma unroll
        for (int i = 0; i < 8; ++i) {
            int idx = tid + i * 256;
            int row = idx >> 4;
            int c   = (idx & 15) * 4;
            float4 v = *(const float4*)&src[(size_t)row * ld + c];
            union { __hip_bfloat16 h[4]; uint2 u; } t;
            t.h[0] = __float2bfloat16(v.x);
            t.h[1] = __float2bfloat16(v.y);
            t.h[2] = __float2bfloat16(v.z);
            t.h[3] = __float2bfloat16(v.w);
            *(uint2*)&dst[row * 72 + c] = t.u;
        }
    }
}

template <typename AT, typename CT>
__device__ inline void gemm_body(
    const AT* __restrict__ A,
    const float* __restrict__ B,
    const float* __restrict__ bias,
    CT* __restrict__ C,
    int M, int N, int K, int bx, int by, int vmode)
{
    __shared__ __hip_bfloat16 sA[128 * 72] __attribute__((aligned(16)));
    __shared__ __hip_bfloat16 sB[128 * 72] __attribute__((aligned(16)));

    const int tid  = threadIdx.x;
    const int lane = tid & 63;
    const int wave = tid >> 6;
    const int quad = lane >> 4;
    const int l16  = lane & 15;
    const int wm   = wave & 1;
    const int wn   = wave >> 1;
    const int m0   = bx * 128;
    const int n0   = by * 128;

    f32x4 acc[4][4];
#pragma unroll
    for (int mt = 0; mt < 4; ++mt)
#pragma unroll
        for (int nt = 0; nt < 4; ++nt)
            acc[mt][nt] = (f32x4)(0.0f);

    for (int k0 = 0; k0 < K; k0 += 64) {
        stage_tile(A + (size_t)m0 * K + k0, K, sA, tid);
        stage_tile(B + (size_t)n0 * K + k0, K, sB, tid);
        __syncthreads();
#pragma unroll
        for (int ks = 0; ks < 2; ++ks) {
            bf16x8 af[4], bfr[4];
#pragma unroll
            for (int mt = 0; mt < 4; ++mt)
                af[mt] = *(const bf16x8*)&sA[(wm * 64 + mt * 16 + l16) * 72 + ks * 32 + quad * 8];
#pragma unroll
            for (int nt = 0; nt < 4; ++nt)
                bfr[nt] = *(const bf16x8*)&sB[(wn * 64 + nt * 16 + l16) * 72 + ks * 32 + quad * 8];
#pragma unroll
            for (int mt = 0; mt < 4; ++mt)
#pragma unroll
                for (int nt = 0; nt < 4; ++nt)
                    acc[mt][nt] = MFMA16(af[mt], bfr[nt], acc[mt][nt]);
        }
        __syncthreads();
    }

    // epilogue. C fragment layout: col = l16 (+tile), row = quad*4+r
    if (vmode == 0) {
#pragma unroll
        for (int nt = 0; nt < 4; ++nt) {
            int col  = n0 + wn * 64 + nt * 16 + l16;
            float bv = bias[col];
#pragma unroll
            for (int mt = 0; mt < 4; ++mt) {
                int rowbase = m0 + wm * 64 + mt * 16 + quad * 4;
#pragma unroll
                for (int r = 0; r < 4; ++r) {
                    float v = acc[mt][nt][r] + bv;
                    if constexpr (sizeof(CT) == 2)
                        C[(size_t)(rowbase + r) * N + col] = __float2bfloat16(v);
                    else
                        C[(size_t)(rowbase + r) * N + col] = v;
                }
            }
        }
    } else {
        // transposed V store: row=(n,s), col=(h,d) -> C[(n*NH+h)*HD + d][s]
        if constexpr (sizeof(CT) == 2) {
#pragma unroll
            for (int nt = 0; nt < 4; ++nt) {
                int col  = n0 + wn * 64 + nt * 16 + l16;
                float bv = bias[col];
                int hh = col >> 6;    // head
                int dd = col & 63;    // dim within head
#pragma unroll
                for (int mt = 0; mt < 4; ++mt) {
                    int rowbase = m0 + wm * 64 + mt * 16 + quad * 4;
                    int nb = rowbase >> 11;      // batch
                    int s0 = rowbase & 2047;     // seq pos (mult of 4)
                    union { __hip_bfloat16 e[4]; uint2 u; } t;
#pragma unroll
                    for (int r = 0; r < 4; ++r)
                        t.e[r] = __float2bfloat16(acc[mt][nt][r] + bv);
                    *(uint2*)&C[((size_t)(nb * NH + hh) * HD + dd) * SEQ + s0] = t.u;
                }
            }
        }
    }
}

__global__ __launch_bounds__(256) void gemm_qkv(
    const float* __restrict__ q, const float* __restrict__ k, const float* __restrict__ v,
    const float* __restrict__ Wq, const float* __restrict__ Wk, const float* __restrict__ Wv,
    const float* __restrict__ bq, const float* __restrict__ bk, const float* __restrict__ bv,
    __hip_bfloat16* __restrict__ qo, __hip_bfloat16* __restrict__ ko, __hip_bfloat16* __restrict__ vo)
{
    const float *A, *B, *bi; __hip_bfloat16* C; int mode = 0;
    switch (blockIdx.z) {
        case 0:  A = q; B = Wq; bi = bq; C = qo; break;
        case 1:  A = k; B = Wk; bi = bk; C = ko; break;
        default: A = v; B = Wv; bi = bv; C = vo; mode = 1; break;
    }
    gemm_body<float, __hip_bfloat16>(A, B, bi, C, MROWS, EMBED, EMBED,
                                     blockIdx.x, blockIdx.y, mode);
}

__global__ __launch_bounds__(256) void gemm_out(
    const __hip_bfloat16* __restrict__ A, const float* __restrict__ B,
    const float* __restrict__ bias, float* __restrict__ C, int M, int N, int K)
{
    gemm_body<__hip_bfloat16, float>(A, B, bias, C, M, N, K,
                                     blockIdx.x, blockIdx.y, 0);
}

// ---------------------------------------------------------------------------
// Fused attention: per block = 64 L-rows of one (n,h).
// Fixed-offset softmax: w = exp(s-MAXC)/sum(exp(s-MAXC))  (== reference).
// Pass 1: QK MFMA -> per-lane partial sums; ONE shuffle reduce after loop.
// Pass 2: recompute scores -> w (fp32 global + bf16 LDS) -> PV MFMA with
//         V^T tiles staged coalesced from the (N,H,D,S)-layout vws.
// ---------------------------------------------------------------------------
__global__ __launch_bounds__(256) void attn_fused(
    const __hip_bfloat16* __restrict__ qws,   // (N,S,E)
    const __hip_bfloat16* __restrict__ kws,   // (N,S,E)
    const __hip_bfloat16* __restrict__ vwsT,  // (N,H,D,S)
    float* __restrict__ wout,                 // (N,H,L,S) fp32
    __hip_bfloat16* __restrict__ attnws)      // (N,L,E) bf16
{
    const int tid  = threadIdx.x;
    const int lane = tid & 63;
    const int wave = tid >> 6;
    const int quad = lane >> 4;
    const int l16  = lane & 15;
    const int lb   = blockIdx.x;
    const int h    = blockIdx.y;
    const int n    = blockIdx.z;

    __shared__ __hip_bfloat16 sK[64 * 72] __attribute__((aligned(16)));
    __shared__ __hip_bfloat16 sVt[64 * 72] __attribute__((aligned(16)));
    __shared__ __hip_bfloat16 sW[64 * 72] __attribute__((aligned(16)));

    const size_t kbase = ((size_t)n * SEQ) * EMBED + h * HD;
    const size_t vbase = ((size_t)(n * NH + h)) * HD * SEQ;

    // Q fragments in registers for the whole kernel (same algebra as old sQ)
    const int qrow = lb * 64 + wave * 16 + l16;
    const bf16x8 a0 = *(const bf16x8*)&qws[kbase + (size_t)qrow * EMBED + quad * 8];
    const bf16x8 a1 = *(const bf16x8*)&qws[kbase + (size_t)qrow * EMBED + 32 + quad * 8];

    float ssum[4] = {0.0f, 0.0f, 0.0f, 0.0f};

    // ---------------- pass 1: row sums of exp(s - MAXC) ----------------
    for (int st = 0; st < 32; ++st) {
#pragma unroll
        for (int i = 0; i < 2; ++i) {
            int idx = tid + i * 256;
            int row = idx >> 3;
            int c   = (idx & 7) * 8;
            *(uint4*)&sK[row * 72 + c] =
                *(const uint4*)&kws[kbase + (size_t)(st * 64 + row) * EMBED + c];
        }
        __syncthreads();

        f32x4 acc[4];
#pragma unroll
        for (int ct = 0; ct < 4; ++ct) acc[ct] = (f32x4)(0.0f);
#pragma unroll
        for (int ct = 0; ct < 4; ++ct) {
            bf16x8 b0 = *(const bf16x8*)&sK[(ct * 16 + l16) * 72 + quad * 8];
            bf16x8 b1 = *(const bf16x8*)&sK[(ct * 16 + l16) * 72 + 32 + quad * 8];
            acc[ct] = MFMA16(a0, b0, acc[ct]);
            acc[ct] = MFMA16(a1, b1, acc[ct]);
        }
        __syncthreads();

#pragma unroll
        for (int ct = 0; ct < 4; ++ct)
#pragma unroll
            for (int r = 0; r < 4; ++r)
                ssum[r] += __expf(acc[ct][r] * SCALING - MAXC);
    }

    // single reduction over the 16 lanes of each row group
#pragma unroll
    for (int off = 1; off < 16; off <<= 1)
#pragma unroll
        for (int r = 0; r < 4; ++r)
            ssum[r] += __shfl_xor(ssum[r], off, 64);
    float linv[4];
#pragma unroll
    for (int r = 0; r < 4; ++r) linv[r] = 1.0f / ssum[r];

    f32x4 acco[4];
#pragma unroll
    for (int ct = 0; ct < 4; ++ct) acco[ct] = (f32x4)(0.0f);

    const size_t wbase = (((size_t)n * NH + h) * SEQ + lb * 64) * (size_t)SEQ;

    // ---------------- pass 2: w write + PV ----------------
    for (int st = 0; st < 32; ++st) {
#pragma unroll
        for (int i = 0; i < 2; ++i) {
            int idx = tid + i * 256;
            int row = idx >> 3;
            int c   = (idx & 7) * 8;
            *(uint4*)&sK[row * 72 + c] =
                *(const uint4*)&kws[kbase + (size_t)(st * 64 + row) * EMBED + c];
            // V^T tile: row = d, cols = s; coalesced copy from (N,H,D,S)
            *(uint4*)&sVt[row * 72 + c] =
                *(const uint4*)&vwsT[vbase + (size_t)row * SEQ + st * 64 + c];
        }
        __syncthreads();

        f32x4 acc[4];
#pragma unroll
        for (int ct = 0; ct < 4; ++ct) acc[ct] = (f32x4)(0.0f);
#pragma unroll
        for (int ct = 0; ct < 4; ++ct) {
            bf16x8 b0 = *(const bf16x8*)&sK[(ct * 16 + l16) * 72 + quad * 8];
            bf16x8 b1 = *(const bf16x8*)&sK[(ct * 16 + l16) * 72 + 32 + quad * 8];
            acc[ct] = MFMA16(a0, b0, acc[ct]);
            acc[ct] = MFMA16(a1, b1, acc[ct]);
        }

        // w: fp32 -> global, bf16 -> sW for PV
#pragma unroll
        for (int ct = 0; ct < 4; ++ct)
#pragma unroll
            for (int r = 0; r < 4; ++r) {
                float wv = __expf(acc[ct][r] * SCALING - MAXC) * linv[r];
                int lr = wave * 16 + quad * 4 + r;
                sW[lr * 72 + ct * 16 + l16] = __float2bfloat16(wv);
                wout[wbase + (size_t)lr * SEQ + st * 64 + ct * 16 + l16] = wv;
            }
        __syncthreads();

        // PV: A = w rows (m=l,k=s), B = V^T rows (n=d,k=s)
        bf16x8 wa0 = *(const bf16x8*)&sW[(wave * 16 + l16) * 72 + quad * 8];
        bf16x8 wa1 = *(const bf16x8*)&sW[(wave * 16 + l16) * 72 + 32 + quad * 8];
#pragma unroll
        for (int ct = 0; ct < 4; ++ct) {
            bf16x8 b0 = *(const bf16x8*)&sVt[(ct * 16 + l16) * 72 + quad * 8];
            bf16x8 b1 = *(const bf16x8*)&sVt[(ct * 16 + l16) * 72 + 32 + quad * 8];
            acco[ct] = MFMA16(wa0, b0, acco[ct]);
            acco[ct] = MFMA16(wa1, b1, acco[ct]);
        }
        __syncthreads();
    }

    // epilogue: attn_out (N,L,E) bf16
#pragma unroll
    for (int ct = 0; ct < 4; ++ct) {
        int d = ct * 16 + l16;
#pragma unroll
        for (int r = 0; r < 4; ++r) {
            int l = lb * 64 + wave * 16 + quad * 4 + r;
            attnws[((size_t)n * SEQ + l) * EMBED + h * HD + d] = __float2bfloat16(acco[ct][r]);
        }
    }
}

extern "C" void kernel_launch(void* const* d_in, const int* in_sizes, int n_in,
                              void* d_out, int out_size, void* d_ws, size_t ws_size,
                              hipStream_t stream) {
    const float* query = (const float*)d_in[0];
    const float* key   = (const float*)d_in[1];
    const float* value = (const float*)d_in[2];
    const float* Wq    = (const float*)d_in[3];
    const float* bq    = (const float*)d_in[4];
    const float* Wk    = (const float*)d_in[5];
    const float* bk    = (const float*)d_in[6];
    const float* Wv    = (const float*)d_in[7];
    const float* bv    = (const float*)d_in[8];
    const float* Wo    = (const float*)d_in[9];
    const float* bo    = (const float*)d_in[10];

    float* out  = (float*)d_out;                 // (N,L,E) fp32
    float* wout = out + (size_t)4194304;         // (N,H,L,S) fp32

    __hip_bfloat16* qws = (__hip_bfloat16*)d_ws; // (N,S,E) bf16
    __hip_bfloat16* kws = qws + (size_t)4194304; // (N,S,E) bf16
    __hip_bfloat16* vws = kws + (size_t)4194304; // (N,H,D,S) bf16 (transposed!)
    __hip_bfloat16* aws = vws + (size_t)4194304; // (N,L,E) bf16

    dim3 blk(256);
    gemm_qkv<<<dim3(MROWS / 128, EMBED / 128, 3), blk, 0, stream>>>(
        query, key, value, Wq, Wk, Wv, bq, bk, bv, qws, kws, vws);

    attn_fused<<<dim3(SEQ / 64, NH, BATCH), blk, 0, stream>>>(qws, kws, vws, wout, aws);

    gemm_out<<<dim3(MROWS / 128, EMBED / 128, 1), blk, 0, stream>>>(
        aws, Wo, bo, out, MROWS, EMBED, EMBED);
}